// Round 12
// baseline (239.540 us; speedup 1.0000x reference)
//
#include <hip/hip_runtime.h>
#include <hip/hip_bf16.h>
#include <math.h>

// GATNet: hh = h@W_emb+b_emb -> GAT(8 heads,32,residual) -> GAT(1 head,32) -> out f32.
// Edge-feature branch of the reference is dead code (del e_feat) -> skipped.
// R24 = R22 resubmission (R23's "container failed twice" audited as infra flake:
// the kernel has NO spin path — ticket winner unique by construction — and all
// failure modes degrade to wrong-answer, not hang/fault; harness logs show infra
// retries in passing rounds too). Structure: 7 dispatches. scan merged into prep
// via fence-free last-block pattern: job-4 blocks complete deg atomics (returned
// value forces completion), sync, thread0 takes a ticket; winner (== gridDim.x-1)
// runs the 256-thread scan inline reading deg via RELAXED agent atomic loads
// (plain pipelined loads — R17's storm was ACQUIRE probes). No threadfence.
// All other kernels byte-identical to R21 (verified 231.8us).
// If this fails again: revert to R21 structure permanently.

#define HDIM 256
#define NHEADS 8
#define ODIM 32

typedef unsigned short u16;
typedef __attribute__((ext_vector_type(8))) short short8;
typedef __attribute__((ext_vector_type(4))) float f32x4;

__device__ __forceinline__ float bf2f(u16 u) { return __uint_as_float(((unsigned)u) << 16); }
__device__ __forceinline__ u16 f2bf(float f) {
    unsigned x = __float_as_uint(f);
    return (u16)((x + 0x7FFFu + ((x >> 16) & 1u)) >> 16);  // RNE
}

// ---------------- prep: batched cvt + B swizzles + deg + inline scan ----------------
__global__ __launch_bounds__(256) void prep_kernel(const float* __restrict__ in_h, const float* __restrict__ W_emb,
                                                   const float* __restrict__ fc1, const float* __restrict__ fc2,
                                                   const int* __restrict__ dstv, int* __restrict__ deg,
                                                   int* __restrict__ offs, int* __restrict__ cursor,
                                                   int* __restrict__ ticket,
                                                   u16* __restrict__ Ah, u16* __restrict__ Bemb,
                                                   u16* __restrict__ Bfc1, u16* __restrict__ Bfc2,
                                                   int n4, int E, int N) {
    int job = blockIdx.y;
    int idx = blockIdx.x * 256 + threadIdx.x;
    if (job == 0) {
        if (idx >= n4) return;
        float4 v = ((const float4*)in_h)[idx];
        ushort4 o = {f2bf(v.x), f2bf(v.y), f2bf(v.z), f2bf(v.w)};
        ((ushort4*)Ah)[idx] = o;
        return;
    }
    if (job == 4) {  // degree count + ticket; last-arriving block runs the scan inline
        __shared__ int tkS;
        __shared__ int wsum[4];
        int old = 0;
        if (idx < E) {
            unsigned d = (unsigned)dstv[idx];
            if (d < (unsigned)N) old = atomicAdd(&deg[d], 1);
        }
        if (old < 0) deg[0] = 0;  // never taken; keeps the data-dependency on the atomic's return
        __syncthreads();          // all this block's deg atomics globally performed
        if (threadIdx.x == 0) tkS = atomicAdd(ticket, 1);
        __syncthreads();
        if (tkS == (int)gridDim.x - 1) {  // winner: every job-4 block's atomics are done
            const int n = N;
            int t = threadIdx.x;
            int chunk = (n + 255) / 256;
            int lo = t * chunk, hi = lo + chunk;
            if (hi > n) hi = n;
            if (lo > n) lo = n;
            int s = 0;
            for (int i = lo; i < hi; i++)
                s += __hip_atomic_load(&deg[i], __ATOMIC_RELAXED, __HIP_MEMORY_SCOPE_AGENT);
            int v = s;
#pragma unroll
            for (int d = 1; d < 64; d <<= 1) {
                int nb = __shfl_up(v, d, 64);
                if ((t & 63) >= d) v += nb;
            }
            if ((t & 63) == 63) wsum[t >> 6] = v;
            __syncthreads();
            int woff = 0;
#pragma unroll
            for (int w = 0; w < 4; w++)
                if (w < (t >> 6)) woff += wsum[w];
            int run = woff + v - s;  // exclusive prefix for this thread's chunk
            for (int i = lo; i < hi; i++) {
                offs[i] = run;
                cursor[i] = run;
                run += __hip_atomic_load(&deg[i], __ATOMIC_RELAXED, __HIP_MEMORY_SCOPE_AGENT);
            }
            if (t == 255) offs[n] = run;
        }
        return;
    }
    const float* B;
    u16* O;
    int K, NC;
    if (job == 1) { B = W_emb; O = Bemb; K = 128; NC = 256; }
    else if (job == 2) { B = fc1; O = Bfc1; K = 256; NC = 256; }
    else { B = fc2; O = Bfc2; K = 256; NC = 32; }
    int KB = K / 32;
    int TOT = (NC / 16) * KB * 64;
    if (idx >= TOT) return;
    int lane = idx & 63;
    int kb = (idx >> 6) % KB;
    int ct = (idx >> 6) / KB;
    int n = ct * 16 + (lane & 15);
    int k0 = kb * 32 + (lane >> 4) * 8;
    u16* dst = O + (size_t)idx * 8;
#pragma unroll
    for (int j = 0; j < 8; j++) dst[j] = f2bf(B[(size_t)(k0 + j) * NC + n]);
}

// ---------------- fused: emb GEMM -> 8KB LDS -> fc1 GEMM + elr1 (16-row tiles); fill tail ----------------
__global__ __launch_bounds__(256) void fused_emb_fc1(const u16* __restrict__ Ah, const u16* __restrict__ Bemb,
                                                     const float* __restrict__ bemb, const u16* __restrict__ Bfc1,
                                                     const float* __restrict__ al, const float* __restrict__ ar,
                                                     u16* __restrict__ hh, u16* __restrict__ feat1,
                                                     u16* __restrict__ el, u16* __restrict__ er,
                                                     const int* __restrict__ src, const int* __restrict__ dstv,
                                                     int* __restrict__ cursor, int* __restrict__ srcs,
                                                     int M, int NB, int E, int N) {
    if ((int)blockIdx.x >= NB) {  // ---- CSR fill tail (block-uniform branch; barriers below stay uniform) ----
        int i = ((int)blockIdx.x - NB) * 256 + (int)threadIdx.x;
        if (i < E) {
            unsigned d = (unsigned)dstv[i];
            if (d < (unsigned)N) {
                int p = atomicAdd(&cursor[d], 1);
                if ((unsigned)p < (unsigned)E) srcs[p] = src[i];
            }
        }
        return;
    }
    __shared__ u16 tile[16 * 256];  // 8 KB, reused: swizzled hh tile, then plain feat1 tile
    const int t = threadIdx.x;
    const int lane = t & 63, w = t >> 6;
    const int rb = (int)blockIdx.x * 16;
    const int m = lane & 15, q = lane >> 4;
    const int arow = rb + m;

    // ---- stage 1: emb GEMM (K=128), this wave's ct = w*4 .. w*4+3 ----
    short8 a0[4];
#pragma unroll
    for (int kb = 0; kb < 4; kb++) {
        if (arow < M) a0[kb] = *(const short8*)(Ah + (size_t)arow * 128 + kb * 32 + q * 8);
        else a0[kb] = (short8){0, 0, 0, 0, 0, 0, 0, 0};
    }
    const short8* B8 = (const short8*)Bemb;
#pragma unroll
    for (int ct2 = 0; ct2 < 4; ct2++) {
        const int ct = w * 4 + ct2;
        f32x4 acc = {0.f, 0.f, 0.f, 0.f};
#pragma unroll
        for (int kb = 0; kb < 4; kb++)
            acc = __builtin_amdgcn_mfma_f32_16x16x32_bf16(a0[kb], B8[(ct * 4 + kb) * 64 + lane], acc, 0, 0, 0);
        float bv = bemb[ct * 16 + m];
#pragma unroll
        for (int r = 0; r < 4; r++) {
            int rl = q * 4 + r;
            int ro = rb + rl;
            u16 hv = 0;
            if (ro < M) {
                hv = f2bf(acc[r] + bv);
                hh[(size_t)ro * 256 + ct * 16 + m] = hv;
            }
            int byte = rl * 512 + (ct * 16 + m) * 2;
            tile[(byte ^ ((rl & 7) << 4)) >> 1] = hv;  // XOR-swizzle: b128 reads below are ~2-way (free)
        }
    }
    __syncthreads();

    // ---- stage 2: fc1 A-fragments straight from LDS (no global hh re-read) ----
    short8 af[8];
    {
        int rl = m;
#pragma unroll
        for (int kb = 0; kb < 8; kb++) {
            int byte = rl * 512 + kb * 64 + q * 16;
            af[kb] = *(const short8*)(tile + ((byte ^ ((rl & 7) << 4)) >> 1));
        }
    }
    __syncthreads();  // all af reads drained before tile is overwritten as feat1 tile

    const short8* Bf = (const short8*)Bfc1;
#pragma unroll
    for (int ct2 = 0; ct2 < 4; ct2++) {
        const int ct = w * 4 + ct2;
        f32x4 acc = {0.f, 0.f, 0.f, 0.f};
#pragma unroll
        for (int kb = 0; kb < 8; kb++)
            acc = __builtin_amdgcn_mfma_f32_16x16x32_bf16(af[kb], Bf[(ct * 8 + kb) * 64 + lane], acc, 0, 0, 0);
#pragma unroll
        for (int r = 0; r < 4; r++) {
            int rl = q * 4 + r;
            int ro = rb + rl;
            u16 v = 0;
            if (ro < M) {
                v = f2bf(acc[r]);
                feat1[(size_t)ro * 256 + ct * 16 + m] = v;
            }
            tile[rl * 256 + ct * 16 + m] = v;  // plain layout for elr epilogue
        }
    }
    __syncthreads();

    // ---- stage 3: el/er epilogue from feat1 tile (16 nodes x 8 heads = 128 tasks) ----
    if (t < 128) {
        int nl = t >> 3, h2 = t & 7;
        int node = rb + nl;
        if (node < M) {
            float a_ = 0.f, b_ = 0.f;
#pragma unroll
            for (int d = 0; d < 32; d++) {
                float fv = bf2f(tile[nl * 256 + h2 * 32 + d]);
                a_ += fv * al[h2 * 32 + d];
                b_ += fv * ar[h2 * 32 + d];
            }
            el[node * 8 + h2] = f2bf(a_);
            er[node * 8 + h2] = f2bf(b_);
        }
    }
}

// exp(leaky_relu(l)); logits O(0.1), max-subtraction unnecessary (identical ratios)
__device__ __forceinline__ float edgew(float l) {
    l = (l > 0.f) ? l : 0.2f * l;
    l = fminf(fmaxf(l, -30.f), 30.f);
    return __expf(l);
}

// ---------------- agg1: dual 32-lane edge streams + SHARDED bn-stats epilogue ----------------
__global__ __launch_bounds__(256) void agg1_fused(const u16* __restrict__ feat, const u16* __restrict__ el,
                                                  const u16* __restrict__ er, const int* __restrict__ offs,
                                                  const int* __restrict__ srcs, u16* __restrict__ rst,
                                                  float* __restrict__ stats_sh, int N, int E) {
    __shared__ float psum[4][256], psq[4][256];  // 8 KB
    const int t = threadIdx.x;
    const int wv = t >> 6;
    const int node = blockIdx.x * 4 + wv;
    const int lane = t & 63;
    const int half = lane >> 5;
    const int sl = lane & 31;
    const int h = sl >> 2;
    const bool valid = node < N;
    int beg = 0, end = 0;
    float ern = 0.f;
    if (valid) {
        beg = offs[node];
        end = offs[node + 1];
        if (beg < 0) beg = 0;
        if (end > E) end = E;
        ern = bf2f(er[node * 8 + h]);
    }
    int cnt = end - beg;
    if (cnt < 0) cnt = 0;
    float acc[8] = {0.f, 0.f, 0.f, 0.f, 0.f, 0.f, 0.f, 0.f};
    float sw = 0.f;
    const int myCnt = (cnt - half + 1) >> 1;  // edges in this half's stream
    const int jb = beg + half;
    int k = 0;
    int k4 = myCnt & ~3;
    for (; k < k4; k += 4) {  // 4-deep pipeline per half (8 edges in flight per wave)
        int j0 = jb + 2 * k;
        int s0 = srcs[j0], s1 = srcs[j0 + 2], s2 = srcs[j0 + 4], s3 = srcs[j0 + 6];
        unsigned c0 = (unsigned)s0 < (unsigned)N, c1 = (unsigned)s1 < (unsigned)N;
        unsigned c2 = (unsigned)s2 < (unsigned)N, c3 = (unsigned)s3 < (unsigned)N;
        s0 = c0 ? s0 : 0; s1 = c1 ? s1 : 0; s2 = c2 ? s2 : 0; s3 = c3 ? s3 : 0;
        u16 e0 = el[s0 * 8 + h], e1 = el[s1 * 8 + h], e2 = el[s2 * 8 + h], e3 = el[s3 * 8 + h];
        short8 f0 = *(const short8*)(feat + (size_t)s0 * 256 + sl * 8);
        short8 f1 = *(const short8*)(feat + (size_t)s1 * 256 + sl * 8);
        short8 f2 = *(const short8*)(feat + (size_t)s2 * 256 + sl * 8);
        short8 f3 = *(const short8*)(feat + (size_t)s3 * 256 + sl * 8);
        float w0 = c0 ? edgew(bf2f(e0) + ern) : 0.f;
        float w1 = c1 ? edgew(bf2f(e1) + ern) : 0.f;
        float w2 = c2 ? edgew(bf2f(e2) + ern) : 0.f;
        float w3 = c3 ? edgew(bf2f(e3) + ern) : 0.f;
        sw += w0 + w1 + w2 + w3;
#pragma unroll
        for (int q = 0; q < 8; q++)
            acc[q] += w0 * bf2f((u16)f0[q]) + w1 * bf2f((u16)f1[q]) + w2 * bf2f((u16)f2[q]) + w3 * bf2f((u16)f3[q]);
    }
    for (; k < myCnt; k++) {
        int j = jb + 2 * k;
        int s = srcs[j];
        if ((unsigned)s >= (unsigned)N) continue;
        float wv2 = edgew(bf2f(el[s * 8 + h]) + ern);
        short8 fv = *(const short8*)(feat + (size_t)s * 256 + sl * 8);
        sw += wv2;
#pragma unroll
        for (int q = 0; q < 8; q++) acc[q] += wv2 * bf2f((u16)fv[q]);
    }
    // combine even/odd halves (lane l <-> l^32)
#pragma unroll
    for (int q = 0; q < 8; q++) acc[q] += __shfl_xor(acc[q], 32, 64);
    sw += __shfl_xor(sw, 32, 64);
    if (half == 0) {
        float inv = 1.f / (sw + 1e-16f);
        short8 o;
#pragma unroll
        for (int q = 0; q < 8; q++) o[q] = (short)f2bf(acc[q] * inv);
        if (valid) *(short8*)(rst + (size_t)node * 256 + sl * 8) = o;
#pragma unroll
        for (int q = 0; q < 8; q++) {
            float v = valid ? bf2f((u16)o[q]) : 0.f;  // stats over bf16-rounded stored values
            psum[wv][sl * 8 + q] = v;
            psq[wv][sl * 8 + q] = v * v;
        }
    }
    __syncthreads();
    // column t reduced over the block's 4 nodes -> shard atomics
    float a = psum[0][t] + psum[1][t] + psum[2][t] + psum[3][t];
    float b = psq[0][t] + psq[1][t] + psq[2][t] + psq[3][t];
    float* shd = stats_sh + (size_t)(blockIdx.x & 63) * 512;
    atomicAdd(&shd[t], a);
    atomicAdd(&shd[256 + t], b);
}

// ---------------- fc2 GEMM: prologue reduces 64 stats shards; rest identical ----------------
__global__ __launch_bounds__(256) void gemm_fc2_fused(const u16* __restrict__ rst, const u16* __restrict__ hh,
                                                      const float* __restrict__ stats_sh, const float* __restrict__ g,
                                                      const float* __restrict__ b, const u16* __restrict__ Bsw,
                                                      const float* __restrict__ al2, const float* __restrict__ ar2,
                                                      float* __restrict__ feat2, float* __restrict__ el2,
                                                      float* __restrict__ er2, int M, float invN) {
    __shared__ float sc[256], sh[256];
    __shared__ float red[2][256];   // partial acc from waves 2,3 (per ct: 64 lanes x f32x4)
    __shared__ float tile[16][32];
    const int t = threadIdx.x;
    {
        float sum = 0.f, sq = 0.f;
#pragma unroll 8
        for (int s = 0; s < 64; s++) {
            sum += stats_sh[s * 512 + t];
            sq += stats_sh[s * 512 + 256 + t];
        }
        float mu = sum * invN;
        float var = fmaxf(sq * invN - mu * mu, 0.f);
        float s = g[t] * rsqrtf(var + 1e-5f);
        sc[t] = s;
        sh[t] = b[t] - mu * s;
    }
    __syncthreads();
    const int lane = t & 63, w = t >> 6;
    const int ct = w & 1, kh = w >> 1;
    const int rb = (int)blockIdx.x * 16;
    const int m = lane & 15, q = lane >> 4;
    const int row = rb + m;
    short8 a[4];
#pragma unroll
    for (int j = 0; j < 4; j++) {
        if (row < M) {
            int k0 = (kh * 4 + j) * 32 + q * 8;
            ushort4 r01 = *(const ushort4*)(rst + (size_t)row * 256 + k0);
            ushort4 r23 = *(const ushort4*)(rst + (size_t)row * 256 + k0 + 4);
            ushort4 h01 = *(const ushort4*)(hh + (size_t)row * 256 + k0);
            ushort4 h23 = *(const ushort4*)(hh + (size_t)row * 256 + k0 + 4);
            u16 rv[8] = {r01.x, r01.y, r01.z, r01.w, r23.x, r23.y, r23.z, r23.w};
            u16 hv[8] = {h01.x, h01.y, h01.z, h01.w, h23.x, h23.y, h23.z, h23.w};
            short8 av;
#pragma unroll
            for (int jj = 0; jj < 8; jj++) {
                int c = k0 + jj;
                float y = sc[c] * bf2f(rv[jj]) + sh[c];
                y = (y > 0.f) ? y : expm1f(y);
                av[jj] = (short)f2bf(bf2f(hv[jj]) + y);
            }
            a[j] = av;
        } else a[j] = (short8){0, 0, 0, 0, 0, 0, 0, 0};
    }
    const short8* B8 = (const short8*)Bsw;
    f32x4 acc = {0.f, 0.f, 0.f, 0.f};
#pragma unroll
    for (int j = 0; j < 4; j++)
        acc = __builtin_amdgcn_mfma_f32_16x16x32_bf16(a[j], B8[(ct * 8 + kh * 4 + j) * 64 + lane], acc, 0, 0, 0);
    if (kh == 1) *(f32x4*)&red[ct][lane * 4] = acc;
    __syncthreads();
    if (kh == 0) {
        f32x4 p = *(const f32x4*)&red[ct][lane * 4];
#pragma unroll
        for (int r = 0; r < 4; r++) {
            int rl = q * 4 + r;
            int ro = rb + rl;
            float v = 0.f;
            if (ro < M) {
                v = acc[r] + p[r];
                feat2[(size_t)ro * 32 + ct * 16 + m] = v;
            }
            tile[rl][ct * 16 + m] = v;
        }
    }
    __syncthreads();
    if (t < 16) {
        int node = rb + t;
        if (node < M) {
            float a_ = 0.f, b_ = 0.f;
#pragma unroll
            for (int d = 0; d < 32; d++) {
                float fv = tile[t][d];
                a_ += fv * al2[d];
                b_ += fv * ar2[d];
            }
            el2[node] = a_;
            er2[node] = b_;
        }
    }
}

// ---------------- agg2: 4-deep pipeline + SHARDED stats2 epilogue ----------------
__global__ __launch_bounds__(256) void agg2_fused(const float* __restrict__ feat, const float* __restrict__ el,
                                                  const float* __restrict__ er, const int* __restrict__ offs,
                                                  const int* __restrict__ srcs, float* __restrict__ rst,
                                                  float* __restrict__ stats2_sh, int N, int E) {
    __shared__ float ss[256], ss2[256];
    const int t = threadIdx.x;
    const int node = blockIdx.x * 8 + (t >> 5);
    const int d = t & 31;
    const bool valid = node < N;
    float v = 0.f;
    if (valid) {
        int beg = offs[node], end = offs[node + 1];
        if (beg < 0) beg = 0;
        if (end > E) end = E;
        float ern = er[node];
        float acc = 0.f, sw = 0.f;
        int j = beg;
        int end4 = beg + ((end - beg) & ~3);
        for (; j < end4; j += 4) {  // 4-deep software pipeline
            int s0 = srcs[j], s1 = srcs[j + 1], s2 = srcs[j + 2], s3 = srcs[j + 3];
            unsigned c0 = (unsigned)s0 < (unsigned)N, c1 = (unsigned)s1 < (unsigned)N;
            unsigned c2 = (unsigned)s2 < (unsigned)N, c3 = (unsigned)s3 < (unsigned)N;
            s0 = c0 ? s0 : 0; s1 = c1 ? s1 : 0; s2 = c2 ? s2 : 0; s3 = c3 ? s3 : 0;
            float e0 = el[s0], e1 = el[s1], e2 = el[s2], e3 = el[s3];
            float f0 = feat[(size_t)s0 * 32 + d];
            float f1 = feat[(size_t)s1 * 32 + d];
            float f2 = feat[(size_t)s2 * 32 + d];
            float f3 = feat[(size_t)s3 * 32 + d];
            float w0 = c0 ? edgew(e0 + ern) : 0.f;
            float w1 = c1 ? edgew(e1 + ern) : 0.f;
            float w2 = c2 ? edgew(e2 + ern) : 0.f;
            float w3 = c3 ? edgew(e3 + ern) : 0.f;
            sw += w0; acc += w0 * f0;
            sw += w1; acc += w1 * f1;
            sw += w2; acc += w2 * f2;
            sw += w3; acc += w3 * f3;
        }
        for (; j < end; j++) {
            int s = srcs[j];
            if ((unsigned)s >= (unsigned)N) continue;
            float wv = edgew(el[s] + ern);
            sw += wv;
            acc += wv * feat[(size_t)s * 32 + d];
        }
        v = acc / (sw + 1e-16f);
        rst[(size_t)node * 32 + d] = v;
    }
    ss[t] = valid ? v : 0.f;
    ss2[t] = valid ? v * v : 0.f;
    __syncthreads();
    if (t < 32) {
        float a = 0.f, b = 0.f;
#pragma unroll
        for (int rg = 0; rg < 8; rg++) {
            a += ss[rg * 32 + t];
            b += ss2[rg * 32 + t];
        }
        float* shd = stats2_sh + (size_t)(blockIdx.x & 31) * 64;
        atomicAdd(&shd[t], a);
        atomicAdd(&shd[32 + t], b);
    }
}

// ---------------- final bn + elu -> f32 out; prologue reduces 32 stats2 shards ----------------
__global__ __launch_bounds__(256) void bn_apply2(const float* __restrict__ rst, const float* __restrict__ stats2_sh,
                                                 const float* __restrict__ g, const float* __restrict__ b,
                                                 float* __restrict__ out, int total4, float invN) {
    __shared__ float st[64];
    int t = threadIdx.x;
    if (t < 64) {
        float a = 0.f;
#pragma unroll
        for (int s = 0; s < 32; s++) a += stats2_sh[s * 64 + t];
        st[t] = a;
    }
    __syncthreads();
    int idx = blockIdx.x * 256 + t;
    if (idx >= total4) return;
    float4 v = ((const float4*)rst)[idx];
    int c0 = (idx * 4) & 31;
    float r[4] = {v.x, v.y, v.z, v.w};
#pragma unroll
    for (int j = 0; j < 4; j++) {
        int c = c0 + j;
        float mu = st[c] * invN;
        float var = fmaxf(st[32 + c] * invN - mu * mu, 0.f);
        float y = g[c] * (r[j] - mu) * rsqrtf(var + 1e-5f) + b[c];
        r[j] = (y > 0.f) ? y : expm1f(y);
    }
    float4 o = {r[0], r[1], r[2], r[3]};
    ((float4*)out)[idx] = o;
}

extern "C" void kernel_launch(void* const* d_in, const int* in_sizes, int n_in, void* d_out, int out_size, void* d_ws,
                              size_t ws_size, hipStream_t stream) {
    const int N = out_size / ODIM;
    const int E = in_sizes[2];

    const int* src = (const int*)d_in[2];
    const int* dst = (const int*)d_in[3];
    const float* in_h = (const float*)d_in[0];
    const float* W_emb = (const float*)d_in[4];  const float* b_emb = (const float*)d_in[5];
    const float* fc1 = (const float*)d_in[18];   const float* al1 = (const float*)d_in[19];
    const float* ar1 = (const float*)d_in[20];
    const float* g1 = (const float*)d_in[21];    const float* b1 = (const float*)d_in[22];
    const float* fc2 = (const float*)d_in[23];   const float* al2 = (const float*)d_in[24];
    const float* ar2 = (const float*)d_in[25];
    const float* g2 = (const float*)d_in[26];    const float* b2 = (const float*)d_in[27];
    float* out = (float*)d_out;

    // ---- ws layout (~26 MB) ----
    char* base = (char*)d_ws;
    size_t off = 0;
    auto alloc = [&](size_t bytes) { void* p = base + off; off += (bytes + 63) & ~63ull; return p; };
    const size_t ZBYTES = (size_t)N * 4 + 64 * 512 * 4 + 32 * 64 * 4 + 64;  // deg + shards + shards2 + ticket
    char* zb   = (char*)alloc(ZBYTES);
    int* deg   = (int*)zb;
    float* stats_sh  = (float*)(zb + (size_t)N * 4);
    float* stats2_sh = stats_sh + 64 * 512;
    int* ticket = (int*)(stats2_sh + 32 * 64);
    int* offs  = (int*)alloc((size_t)(N + 1) * 4);
    int* cursor = (int*)alloc((size_t)N * 4);
    int* srcs  = (int*)alloc((size_t)E * 4);
    u16* Ah    = (u16*)alloc((size_t)N * 128 * 2);
    u16* Bemb  = (u16*)alloc((size_t)128 * 256 * 2);
    u16* Bfc1  = (u16*)alloc((size_t)256 * 256 * 2);
    u16* Bfc2  = (u16*)alloc((size_t)256 * 32 * 2);
    u16* hh    = (u16*)alloc((size_t)N * HDIM * 2);
    u16* feat1 = (u16*)alloc((size_t)N * HDIM * 2);
    u16* el1   = (u16*)alloc((size_t)N * 8 * 2);
    u16* er1   = (u16*)alloc((size_t)N * 8 * 2);
    u16* rst   = (u16*)alloc((size_t)N * HDIM * 2);
    float* feat2 = (float*)alloc((size_t)N * 32 * 4);
    float* el2 = (float*)alloc((size_t)N * 4);
    float* er2 = (float*)alloc((size_t)N * 4);
    float* rst2 = (float*)alloc((size_t)N * 32 * 4);

    const int NB16 = (N + 15) / 16;
    const int NBF = (E + 255) / 256;  // fill tail blocks

    hipMemsetAsync(zb, 0, ZBYTES, stream);
    prep_kernel<<<dim3((N * 128 / 4 + 255) / 256, 5), 256, 0, stream>>>(in_h, W_emb, fc1, fc2, dst, deg,
                                                                        offs, cursor, ticket,
                                                                        Ah, Bemb, Bfc1, Bfc2, N * 128 / 4, E, N);
    fused_emb_fc1<<<NB16 + NBF, 256, 0, stream>>>(Ah, Bemb, b_emb, Bfc1, al1, ar1, hh, feat1, el1, er1,
                                                  src, dst, cursor, srcs, N, NB16, E, N);
    agg1_fused<<<(N + 3) / 4, 256, 0, stream>>>(feat1, el1, er1, offs, srcs, rst, stats_sh, N, E);
    gemm_fc2_fused<<<NB16, 256, 0, stream>>>(rst, hh, stats_sh, g1, b1, Bfc2, al2, ar2, feat2, el2, er2, N, 1.f / N);
    agg2_fused<<<(N + 7) / 8, 256, 0, stream>>>(feat2, el2, er2, offs, srcs, rst2, stats2_sh, N, E);
    bn_apply2<<<(N * 8 + 255) / 256, 256, 0, stream>>>(rst2, stats2_sh, g2, b2, out, N * 8, 1.f / N);
}

// Round 13
// 229.619 us; speedup vs baseline: 1.0432x; 1.0432x over previous
//
#include <hip/hip_runtime.h>
#include <hip/hip_bf16.h>
#include <math.h>

// GATNet: hh = h@W_emb+b_emb -> GAT(8 heads,32,residual) -> GAT(1 head,32) -> out f32.
// Edge-feature branch of the reference is dead code (del e_feat) -> skipped.
// R25: scan-merge REVERTED (R24: +7.7us vs R21 — inline scan's serial relaxed-atomic
// loads ~17us ate the boundary saving; thesis falsified). R24's profile surfaced
// prep_kernel at 45.2us (HBM 2.7%, VALU 0.6%) -> baseline prep body ~28-35us, the
// LARGEST body in the pipeline. Fix: delete prep's job-0 cvt (its plurality job,
// 1250 blocks / 7.5MB latency-bound) by fusing f32->bf16 conversion into
// fused_emb_fc1's A-load (2x float4 + RNE f2bf in-register; bit-identical fragments;
// Ah buffer deleted). prep = {deg + 3 B-swizzles}, grid dim3(469,4). scan back as
// its own 1-block dispatch (R21-verified). agg1/fc2/agg2/bn_apply2 byte-identical
// to R21 (verified 231.8us).

#define HDIM 256
#define NHEADS 8
#define ODIM 32

typedef unsigned short u16;
typedef __attribute__((ext_vector_type(8))) short short8;
typedef __attribute__((ext_vector_type(4))) float f32x4;

__device__ __forceinline__ float bf2f(u16 u) { return __uint_as_float(((unsigned)u) << 16); }
__device__ __forceinline__ u16 f2bf(float f) {
    unsigned x = __float_as_uint(f);
    return (u16)((x + 0x7FFFu + ((x >> 16) & 1u)) >> 16);  // RNE
}

// ---------------- prep: deg + B swizzles (cvt job deleted in R25) ----------------
__global__ __launch_bounds__(256) void prep_kernel(const float* __restrict__ W_emb,
                                                   const float* __restrict__ fc1, const float* __restrict__ fc2,
                                                   const int* __restrict__ dstv, int* __restrict__ deg,
                                                   u16* __restrict__ Bemb, u16* __restrict__ Bfc1,
                                                   u16* __restrict__ Bfc2, int E, int N) {
    int job = blockIdx.y;
    int idx = blockIdx.x * 256 + threadIdx.x;
    if (job == 0) {  // degree count (deg pre-zeroed by memset)
        if (idx < E) {
            unsigned d = (unsigned)dstv[idx];
            if (d < (unsigned)N) atomicAdd(&deg[d], 1);
        }
        return;
    }
    const float* B;
    u16* O;
    int K, NC;
    if (job == 1) { B = W_emb; O = Bemb; K = 128; NC = 256; }
    else if (job == 2) { B = fc1; O = Bfc1; K = 256; NC = 256; }
    else { B = fc2; O = Bfc2; K = 256; NC = 32; }
    int KB = K / 32;
    int TOT = (NC / 16) * KB * 64;
    if (idx >= TOT) return;
    int lane = idx & 63;
    int kb = (idx >> 6) % KB;
    int ct = (idx >> 6) / KB;
    int n = ct * 16 + (lane & 15);
    int k0 = kb * 32 + (lane >> 4) * 8;
    u16* dst = O + (size_t)idx * 8;
#pragma unroll
    for (int j = 0; j < 8; j++) dst[j] = f2bf(B[(size_t)(k0 + j) * NC + n]);
}

// ---------------- CSR scan (wave-parallel, 1 block) ----------------
__global__ __launch_bounds__(256) void scan_kernel(const int* __restrict__ deg, int* __restrict__ offs,
                                                   int* __restrict__ cursor, int n) {
    __shared__ int wsum[4];
    int t = threadIdx.x;
    int chunk = (n + 255) / 256;
    int lo = t * chunk, hi = lo + chunk;
    if (hi > n) hi = n;
    if (lo > n) lo = n;
    int s = 0;
    for (int i = lo; i < hi; i++) s += deg[i];
    // inclusive wave scan of s
    int v = s;
#pragma unroll
    for (int d = 1; d < 64; d <<= 1) {
        int nb = __shfl_up(v, d, 64);
        if ((t & 63) >= d) v += nb;
    }
    if ((t & 63) == 63) wsum[t >> 6] = v;
    __syncthreads();
    int woff = 0;
#pragma unroll
    for (int w = 0; w < 4; w++)
        if (w < (t >> 6)) woff += wsum[w];
    int run = woff + v - s;  // exclusive prefix for this thread's chunk
    for (int i = lo; i < hi; i++) {
        offs[i] = run;
        cursor[i] = run;
        run += deg[i];
    }
    if (t == 255) offs[n] = run;  // thread 255's chunk is clamped at n -> run == total
}

// ---------------- fused: emb GEMM (A from f32 in_h, inline cvt) -> LDS -> fc1 + elr1; fill tail ----------------
__global__ __launch_bounds__(256) void fused_emb_fc1(const float* __restrict__ in_h, const u16* __restrict__ Bemb,
                                                     const float* __restrict__ bemb, const u16* __restrict__ Bfc1,
                                                     const float* __restrict__ al, const float* __restrict__ ar,
                                                     u16* __restrict__ hh, u16* __restrict__ feat1,
                                                     u16* __restrict__ el, u16* __restrict__ er,
                                                     const int* __restrict__ src, const int* __restrict__ dstv,
                                                     int* __restrict__ cursor, int* __restrict__ srcs,
                                                     int M, int NB, int E, int N) {
    if ((int)blockIdx.x >= NB) {  // ---- CSR fill tail (block-uniform branch; barriers below stay uniform) ----
        int i = ((int)blockIdx.x - NB) * 256 + (int)threadIdx.x;
        if (i < E) {
            unsigned d = (unsigned)dstv[i];
            if (d < (unsigned)N) {
                int p = atomicAdd(&cursor[d], 1);
                if ((unsigned)p < (unsigned)E) srcs[p] = src[i];
            }
        }
        return;
    }
    __shared__ u16 tile[16 * 256];  // 8 KB, reused: swizzled hh tile, then plain feat1 tile
    const int t = threadIdx.x;
    const int lane = t & 63, w = t >> 6;
    const int rb = (int)blockIdx.x * 16;
    const int m = lane & 15, q = lane >> 4;
    const int arow = rb + m;

    // ---- stage 1: emb GEMM (K=128); A loaded from f32 in_h with inline RNE cvt (R25) ----
    short8 a0[4];
#pragma unroll
    for (int kb = 0; kb < 4; kb++) {
        if (arow < M) {
            const float* hp = in_h + (size_t)arow * 128 + kb * 32 + q * 8;
            float4 v0 = *(const float4*)(hp);
            float4 v1 = *(const float4*)(hp + 4);
            short8 av;
            av[0] = (short)f2bf(v0.x); av[1] = (short)f2bf(v0.y);
            av[2] = (short)f2bf(v0.z); av[3] = (short)f2bf(v0.w);
            av[4] = (short)f2bf(v1.x); av[5] = (short)f2bf(v1.y);
            av[6] = (short)f2bf(v1.z); av[7] = (short)f2bf(v1.w);
            a0[kb] = av;
        } else a0[kb] = (short8){0, 0, 0, 0, 0, 0, 0, 0};
    }
    const short8* B8 = (const short8*)Bemb;
#pragma unroll
    for (int ct2 = 0; ct2 < 4; ct2++) {
        const int ct = w * 4 + ct2;
        f32x4 acc = {0.f, 0.f, 0.f, 0.f};
#pragma unroll
        for (int kb = 0; kb < 4; kb++)
            acc = __builtin_amdgcn_mfma_f32_16x16x32_bf16(a0[kb], B8[(ct * 4 + kb) * 64 + lane], acc, 0, 0, 0);
        float bv = bemb[ct * 16 + m];
#pragma unroll
        for (int r = 0; r < 4; r++) {
            int rl = q * 4 + r;
            int ro = rb + rl;
            u16 hv = 0;
            if (ro < M) {
                hv = f2bf(acc[r] + bv);
                hh[(size_t)ro * 256 + ct * 16 + m] = hv;
            }
            int byte = rl * 512 + (ct * 16 + m) * 2;
            tile[(byte ^ ((rl & 7) << 4)) >> 1] = hv;  // XOR-swizzle: b128 reads below are ~2-way (free)
        }
    }
    __syncthreads();

    // ---- stage 2: fc1 A-fragments straight from LDS (no global hh re-read) ----
    short8 af[8];
    {
        int rl = m;
#pragma unroll
        for (int kb = 0; kb < 8; kb++) {
            int byte = rl * 512 + kb * 64 + q * 16;
            af[kb] = *(const short8*)(tile + ((byte ^ ((rl & 7) << 4)) >> 1));
        }
    }
    __syncthreads();  // all af reads drained before tile is overwritten as feat1 tile

    const short8* Bf = (const short8*)Bfc1;
#pragma unroll
    for (int ct2 = 0; ct2 < 4; ct2++) {
        const int ct = w * 4 + ct2;
        f32x4 acc = {0.f, 0.f, 0.f, 0.f};
#pragma unroll
        for (int kb = 0; kb < 8; kb++)
            acc = __builtin_amdgcn_mfma_f32_16x16x32_bf16(af[kb], Bf[(ct * 8 + kb) * 64 + lane], acc, 0, 0, 0);
#pragma unroll
        for (int r = 0; r < 4; r++) {
            int rl = q * 4 + r;
            int ro = rb + rl;
            u16 v = 0;
            if (ro < M) {
                v = f2bf(acc[r]);
                feat1[(size_t)ro * 256 + ct * 16 + m] = v;
            }
            tile[rl * 256 + ct * 16 + m] = v;  // plain layout for elr epilogue
        }
    }
    __syncthreads();

    // ---- stage 3: el/er epilogue from feat1 tile (16 nodes x 8 heads = 128 tasks) ----
    if (t < 128) {
        int nl = t >> 3, h2 = t & 7;
        int node = rb + nl;
        if (node < M) {
            float a_ = 0.f, b_ = 0.f;
#pragma unroll
            for (int d = 0; d < 32; d++) {
                float fv = bf2f(tile[nl * 256 + h2 * 32 + d]);
                a_ += fv * al[h2 * 32 + d];
                b_ += fv * ar[h2 * 32 + d];
            }
            el[node * 8 + h2] = f2bf(a_);
            er[node * 8 + h2] = f2bf(b_);
        }
    }
}

// exp(leaky_relu(l)); logits O(0.1), max-subtraction unnecessary (identical ratios)
__device__ __forceinline__ float edgew(float l) {
    l = (l > 0.f) ? l : 0.2f * l;
    l = fminf(fmaxf(l, -30.f), 30.f);
    return __expf(l);
}

// ---------------- agg1: dual 32-lane edge streams + SHARDED bn-stats epilogue ----------------
__global__ __launch_bounds__(256) void agg1_fused(const u16* __restrict__ feat, const u16* __restrict__ el,
                                                  const u16* __restrict__ er, const int* __restrict__ offs,
                                                  const int* __restrict__ srcs, u16* __restrict__ rst,
                                                  float* __restrict__ stats_sh, int N, int E) {
    __shared__ float psum[4][256], psq[4][256];  // 8 KB
    const int t = threadIdx.x;
    const int wv = t >> 6;
    const int node = blockIdx.x * 4 + wv;
    const int lane = t & 63;
    const int half = lane >> 5;
    const int sl = lane & 31;
    const int h = sl >> 2;
    const bool valid = node < N;
    int beg = 0, end = 0;
    float ern = 0.f;
    if (valid) {
        beg = offs[node];
        end = offs[node + 1];
        if (beg < 0) beg = 0;
        if (end > E) end = E;
        ern = bf2f(er[node * 8 + h]);
    }
    int cnt = end - beg;
    if (cnt < 0) cnt = 0;
    float acc[8] = {0.f, 0.f, 0.f, 0.f, 0.f, 0.f, 0.f, 0.f};
    float sw = 0.f;
    const int myCnt = (cnt - half + 1) >> 1;  // edges in this half's stream
    const int jb = beg + half;
    int k = 0;
    int k4 = myCnt & ~3;
    for (; k < k4; k += 4) {  // 4-deep pipeline per half (8 edges in flight per wave)
        int j0 = jb + 2 * k;
        int s0 = srcs[j0], s1 = srcs[j0 + 2], s2 = srcs[j0 + 4], s3 = srcs[j0 + 6];
        unsigned c0 = (unsigned)s0 < (unsigned)N, c1 = (unsigned)s1 < (unsigned)N;
        unsigned c2 = (unsigned)s2 < (unsigned)N, c3 = (unsigned)s3 < (unsigned)N;
        s0 = c0 ? s0 : 0; s1 = c1 ? s1 : 0; s2 = c2 ? s2 : 0; s3 = c3 ? s3 : 0;
        u16 e0 = el[s0 * 8 + h], e1 = el[s1 * 8 + h], e2 = el[s2 * 8 + h], e3 = el[s3 * 8 + h];
        short8 f0 = *(const short8*)(feat + (size_t)s0 * 256 + sl * 8);
        short8 f1 = *(const short8*)(feat + (size_t)s1 * 256 + sl * 8);
        short8 f2 = *(const short8*)(feat + (size_t)s2 * 256 + sl * 8);
        short8 f3 = *(const short8*)(feat + (size_t)s3 * 256 + sl * 8);
        float w0 = c0 ? edgew(bf2f(e0) + ern) : 0.f;
        float w1 = c1 ? edgew(bf2f(e1) + ern) : 0.f;
        float w2 = c2 ? edgew(bf2f(e2) + ern) : 0.f;
        float w3 = c3 ? edgew(bf2f(e3) + ern) : 0.f;
        sw += w0 + w1 + w2 + w3;
#pragma unroll
        for (int q = 0; q < 8; q++)
            acc[q] += w0 * bf2f((u16)f0[q]) + w1 * bf2f((u16)f1[q]) + w2 * bf2f((u16)f2[q]) + w3 * bf2f((u16)f3[q]);
    }
    for (; k < myCnt; k++) {
        int j = jb + 2 * k;
        int s = srcs[j];
        if ((unsigned)s >= (unsigned)N) continue;
        float wv2 = edgew(bf2f(el[s * 8 + h]) + ern);
        short8 fv = *(const short8*)(feat + (size_t)s * 256 + sl * 8);
        sw += wv2;
#pragma unroll
        for (int q = 0; q < 8; q++) acc[q] += wv2 * bf2f((u16)fv[q]);
    }
    // combine even/odd halves (lane l <-> l^32)
#pragma unroll
    for (int q = 0; q < 8; q++) acc[q] += __shfl_xor(acc[q], 32, 64);
    sw += __shfl_xor(sw, 32, 64);
    if (half == 0) {
        float inv = 1.f / (sw + 1e-16f);
        short8 o;
#pragma unroll
        for (int q = 0; q < 8; q++) o[q] = (short)f2bf(acc[q] * inv);
        if (valid) *(short8*)(rst + (size_t)node * 256 + sl * 8) = o;
#pragma unroll
        for (int q = 0; q < 8; q++) {
            float v = valid ? bf2f((u16)o[q]) : 0.f;  // stats over bf16-rounded stored values
            psum[wv][sl * 8 + q] = v;
            psq[wv][sl * 8 + q] = v * v;
        }
    }
    __syncthreads();
    // column t reduced over the block's 4 nodes -> shard atomics
    float a = psum[0][t] + psum[1][t] + psum[2][t] + psum[3][t];
    float b = psq[0][t] + psq[1][t] + psq[2][t] + psq[3][t];
    float* shd = stats_sh + (size_t)(blockIdx.x & 63) * 512;
    atomicAdd(&shd[t], a);
    atomicAdd(&shd[256 + t], b);
}

// ---------------- fc2 GEMM: prologue reduces 64 stats shards; rest identical ----------------
__global__ __launch_bounds__(256) void gemm_fc2_fused(const u16* __restrict__ rst, const u16* __restrict__ hh,
                                                      const float* __restrict__ stats_sh, const float* __restrict__ g,
                                                      const float* __restrict__ b, const u16* __restrict__ Bsw,
                                                      const float* __restrict__ al2, const float* __restrict__ ar2,
                                                      float* __restrict__ feat2, float* __restrict__ el2,
                                                      float* __restrict__ er2, int M, float invN) {
    __shared__ float sc[256], sh[256];
    __shared__ float red[2][256];   // partial acc from waves 2,3 (per ct: 64 lanes x f32x4)
    __shared__ float tile[16][32];
    const int t = threadIdx.x;
    {
        float sum = 0.f, sq = 0.f;
#pragma unroll 8
        for (int s = 0; s < 64; s++) {
            sum += stats_sh[s * 512 + t];
            sq += stats_sh[s * 512 + 256 + t];
        }
        float mu = sum * invN;
        float var = fmaxf(sq * invN - mu * mu, 0.f);
        float s = g[t] * rsqrtf(var + 1e-5f);
        sc[t] = s;
        sh[t] = b[t] - mu * s;
    }
    __syncthreads();
    const int lane = t & 63, w = t >> 6;
    const int ct = w & 1, kh = w >> 1;
    const int rb = (int)blockIdx.x * 16;
    const int m = lane & 15, q = lane >> 4;
    const int row = rb + m;
    short8 a[4];
#pragma unroll
    for (int j = 0; j < 4; j++) {
        if (row < M) {
            int k0 = (kh * 4 + j) * 32 + q * 8;
            ushort4 r01 = *(const ushort4*)(rst + (size_t)row * 256 + k0);
            ushort4 r23 = *(const ushort4*)(rst + (size_t)row * 256 + k0 + 4);
            ushort4 h01 = *(const ushort4*)(hh + (size_t)row * 256 + k0);
            ushort4 h23 = *(const ushort4*)(hh + (size_t)row * 256 + k0 + 4);
            u16 rv[8] = {r01.x, r01.y, r01.z, r01.w, r23.x, r23.y, r23.z, r23.w};
            u16 hv[8] = {h01.x, h01.y, h01.z, h01.w, h23.x, h23.y, h23.z, h23.w};
            short8 av;
#pragma unroll
            for (int jj = 0; jj < 8; jj++) {
                int c = k0 + jj;
                float y = sc[c] * bf2f(rv[jj]) + sh[c];
                y = (y > 0.f) ? y : expm1f(y);
                av[jj] = (short)f2bf(bf2f(hv[jj]) + y);
            }
            a[j] = av;
        } else a[j] = (short8){0, 0, 0, 0, 0, 0, 0, 0};
    }
    const short8* B8 = (const short8*)Bsw;
    f32x4 acc = {0.f, 0.f, 0.f, 0.f};
#pragma unroll
    for (int j = 0; j < 4; j++)
        acc = __builtin_amdgcn_mfma_f32_16x16x32_bf16(a[j], B8[(ct * 8 + kh * 4 + j) * 64 + lane], acc, 0, 0, 0);
    if (kh == 1) *(f32x4*)&red[ct][lane * 4] = acc;
    __syncthreads();
    if (kh == 0) {
        f32x4 p = *(const f32x4*)&red[ct][lane * 4];
#pragma unroll
        for (int r = 0; r < 4; r++) {
            int rl = q * 4 + r;
            int ro = rb + rl;
            float v = 0.f;
            if (ro < M) {
                v = acc[r] + p[r];
                feat2[(size_t)ro * 32 + ct * 16 + m] = v;
            }
            tile[rl][ct * 16 + m] = v;
        }
    }
    __syncthreads();
    if (t < 16) {
        int node = rb + t;
        if (node < M) {
            float a_ = 0.f, b_ = 0.f;
#pragma unroll
            for (int d = 0; d < 32; d++) {
                float fv = tile[t][d];
                a_ += fv * al2[d];
                b_ += fv * ar2[d];
            }
            el2[node] = a_;
            er2[node] = b_;
        }
    }
}

// ---------------- agg2: 4-deep pipeline + SHARDED stats2 epilogue ----------------
__global__ __launch_bounds__(256) void agg2_fused(const float* __restrict__ feat, const float* __restrict__ el,
                                                  const float* __restrict__ er, const int* __restrict__ offs,
                                                  const int* __restrict__ srcs, float* __restrict__ rst,
                                                  float* __restrict__ stats2_sh, int N, int E) {
    __shared__ float ss[256], ss2[256];
    const int t = threadIdx.x;
    const int node = blockIdx.x * 8 + (t >> 5);
    const int d = t & 31;
    const bool valid = node < N;
    float v = 0.f;
    if (valid) {
        int beg = offs[node], end = offs[node + 1];
        if (beg < 0) beg = 0;
        if (end > E) end = E;
        float ern = er[node];
        float acc = 0.f, sw = 0.f;
        int j = beg;
        int end4 = beg + ((end - beg) & ~3);
        for (; j < end4; j += 4) {  // 4-deep software pipeline
            int s0 = srcs[j], s1 = srcs[j + 1], s2 = srcs[j + 2], s3 = srcs[j + 3];
            unsigned c0 = (unsigned)s0 < (unsigned)N, c1 = (unsigned)s1 < (unsigned)N;
            unsigned c2 = (unsigned)s2 < (unsigned)N, c3 = (unsigned)s3 < (unsigned)N;
            s0 = c0 ? s0 : 0; s1 = c1 ? s1 : 0; s2 = c2 ? s2 : 0; s3 = c3 ? s3 : 0;
            float e0 = el[s0], e1 = el[s1], e2 = el[s2], e3 = el[s3];
            float f0 = feat[(size_t)s0 * 32 + d];
            float f1 = feat[(size_t)s1 * 32 + d];
            float f2 = feat[(size_t)s2 * 32 + d];
            float f3 = feat[(size_t)s3 * 32 + d];
            float w0 = c0 ? edgew(e0 + ern) : 0.f;
            float w1 = c1 ? edgew(e1 + ern) : 0.f;
            float w2 = c2 ? edgew(e2 + ern) : 0.f;
            float w3 = c3 ? edgew(e3 + ern) : 0.f;
            sw += w0; acc += w0 * f0;
            sw += w1; acc += w1 * f1;
            sw += w2; acc += w2 * f2;
            sw += w3; acc += w3 * f3;
        }
        for (; j < end; j++) {
            int s = srcs[j];
            if ((unsigned)s >= (unsigned)N) continue;
            float wv = edgew(el[s] + ern);
            sw += wv;
            acc += wv * feat[(size_t)s * 32 + d];
        }
        v = acc / (sw + 1e-16f);
        rst[(size_t)node * 32 + d] = v;
    }
    ss[t] = valid ? v : 0.f;
    ss2[t] = valid ? v * v : 0.f;
    __syncthreads();
    if (t < 32) {
        float a = 0.f, b = 0.f;
#pragma unroll
        for (int rg = 0; rg < 8; rg++) {
            a += ss[rg * 32 + t];
            b += ss2[rg * 32 + t];
        }
        float* shd = stats2_sh + (size_t)(blockIdx.x & 31) * 64;
        atomicAdd(&shd[t], a);
        atomicAdd(&shd[32 + t], b);
    }
}

// ---------------- final bn + elu -> f32 out; prologue reduces 32 stats2 shards ----------------
__global__ __launch_bounds__(256) void bn_apply2(const float* __restrict__ rst, const float* __restrict__ stats2_sh,
                                                 const float* __restrict__ g, const float* __restrict__ b,
                                                 float* __restrict__ out, int total4, float invN) {
    __shared__ float st[64];
    int t = threadIdx.x;
    if (t < 64) {
        float a = 0.f;
#pragma unroll
        for (int s = 0; s < 32; s++) a += stats2_sh[s * 64 + t];
        st[t] = a;
    }
    __syncthreads();
    int idx = blockIdx.x * 256 + t;
    if (idx >= total4) return;
    float4 v = ((const float4*)rst)[idx];
    int c0 = (idx * 4) & 31;
    float r[4] = {v.x, v.y, v.z, v.w};
#pragma unroll
    for (int j = 0; j < 4; j++) {
        int c = c0 + j;
        float mu = st[c] * invN;
        float var = fmaxf(st[32 + c] * invN - mu * mu, 0.f);
        float y = g[c] * (r[j] - mu) * rsqrtf(var + 1e-5f) + b[c];
        r[j] = (y > 0.f) ? y : expm1f(y);
    }
    float4 o = {r[0], r[1], r[2], r[3]};
    ((float4*)out)[idx] = o;
}

extern "C" void kernel_launch(void* const* d_in, const int* in_sizes, int n_in, void* d_out, int out_size, void* d_ws,
                              size_t ws_size, hipStream_t stream) {
    const int N = out_size / ODIM;
    const int E = in_sizes[2];

    const int* src = (const int*)d_in[2];
    const int* dst = (const int*)d_in[3];
    const float* in_h = (const float*)d_in[0];
    const float* W_emb = (const float*)d_in[4];  const float* b_emb = (const float*)d_in[5];
    const float* fc1 = (const float*)d_in[18];   const float* al1 = (const float*)d_in[19];
    const float* ar1 = (const float*)d_in[20];
    const float* g1 = (const float*)d_in[21];    const float* b1 = (const float*)d_in[22];
    const float* fc2 = (const float*)d_in[23];   const float* al2 = (const float*)d_in[24];
    const float* ar2 = (const float*)d_in[25];
    const float* g2 = (const float*)d_in[26];    const float* b2 = (const float*)d_in[27];
    float* out = (float*)d_out;

    // ---- ws layout (~24 MB) ----
    char* base = (char*)d_ws;
    size_t off = 0;
    auto alloc = [&](size_t bytes) { void* p = base + off; off += (bytes + 63) & ~63ull; return p; };
    const size_t ZBYTES = (size_t)N * 4 + 64 * 512 * 4 + 32 * 64 * 4;  // deg + stats shards + stats2 shards
    char* zb   = (char*)alloc(ZBYTES);
    int* deg   = (int*)zb;
    float* stats_sh  = (float*)(zb + (size_t)N * 4);
    float* stats2_sh = stats_sh + 64 * 512;
    int* offs  = (int*)alloc((size_t)(N + 1) * 4);
    int* cursor = (int*)alloc((size_t)N * 4);
    int* srcs  = (int*)alloc((size_t)E * 4);
    u16* Bemb  = (u16*)alloc((size_t)128 * 256 * 2);
    u16* Bfc1  = (u16*)alloc((size_t)256 * 256 * 2);
    u16* Bfc2  = (u16*)alloc((size_t)256 * 32 * 2);
    u16* hh    = (u16*)alloc((size_t)N * HDIM * 2);
    u16* feat1 = (u16*)alloc((size_t)N * HDIM * 2);
    u16* el1   = (u16*)alloc((size_t)N * 8 * 2);
    u16* er1   = (u16*)alloc((size_t)N * 8 * 2);
    u16* rst   = (u16*)alloc((size_t)N * HDIM * 2);
    float* feat2 = (float*)alloc((size_t)N * 32 * 4);
    float* el2 = (float*)alloc((size_t)N * 4);
    float* er2 = (float*)alloc((size_t)N * 4);
    float* rst2 = (float*)alloc((size_t)N * 32 * 4);

    const int NB16 = (N + 15) / 16;
    const int NBF = (E + 255) / 256;  // fill tail blocks
    int GX = (E + 255) / 256;         // prep grid x: deg needs this; swizzles need <= 32
    if (GX < 32) GX = 32;

    hipMemsetAsync(zb, 0, ZBYTES, stream);
    prep_kernel<<<dim3(GX, 4), 256, 0, stream>>>(W_emb, fc1, fc2, dst, deg, Bemb, Bfc1, Bfc2, E, N);
    scan_kernel<<<1, 256, 0, stream>>>(deg, offs, cursor, N);
    fused_emb_fc1<<<NB16 + NBF, 256, 0, stream>>>(in_h, Bemb, b_emb, Bfc1, al1, ar1, hh, feat1, el1, er1,
                                                  src, dst, cursor, srcs, N, NB16, E, N);
    agg1_fused<<<(N + 3) / 4, 256, 0, stream>>>(feat1, el1, er1, offs, srcs, rst, stats_sh, N, E);
    gemm_fc2_fused<<<NB16, 256, 0, stream>>>(rst, hh, stats_sh, g1, b1, Bfc2, al2, ar2, feat2, el2, er2, N, 1.f / N);
    agg2_fused<<<(N + 7) / 8, 256, 0, stream>>>(feat2, el2, er2, offs, srcs, rst2, stats2_sh, N, E);
    bn_apply2<<<(N * 8 + 255) / 256, 256, 0, stream>>>(rst2, stats2_sh, g2, b2, out, N * 8, 1.f / N);
}